// Round 3
// baseline (5879.129 us; speedup 1.0000x reference)
//
#include <hip/hip_runtime.h>
#include <stdint.h>

// StackedRNN depth-3, B=16, T=2048, H=256. Inputs fp32, output fp32.
// 3 persistent workgroups (one per depth), weights cvt'd once to fp16 and
// resident in VGPRs as MFMA A-fragments, batch=16 folded into MFMA N, depth
// pipelined through d_out (fp32) with chunked agent-scope progress flags.

#define TT 2048
#define HH 256

typedef _Float16 h16x8 __attribute__((ext_vector_type(8)));
typedef float f32x4 __attribute__((ext_vector_type(4)));

__device__ __forceinline__ unsigned pk2h(float a, float b) {
  union { _Float16 h[2]; unsigned u; } v;
  v.h[0] = (_Float16)a;
  v.h[1] = (_Float16)b;
  return v.u;
}

// Eigen-style rational tanh, |err| ~1e-6 on clamped range.
__device__ __forceinline__ float fast_tanh(float x) {
  const float L = 7.90531110763549805f;
  x = fminf(fmaxf(x, -L), L);
  float x2 = x * x;
  float p = -2.76076847742355e-16f;
  p = fmaf(x2, p, 2.00018790482477e-13f);
  p = fmaf(x2, p, -8.60467152213735e-11f);
  p = fmaf(x2, p, 5.12229709037114e-08f);
  p = fmaf(x2, p, 1.48572235717979e-05f);
  p = fmaf(x2, p, 6.37261928875436e-04f);
  p = fmaf(x2, p, 4.89352455891786e-03f);
  p = x * p;
  float qd = 1.19825839466702e-06f;
  qd = fmaf(x2, qd, 1.18534705686654e-04f);
  qd = fmaf(x2, qd, 2.26843463243900e-03f);
  qd = fmaf(x2, qd, 4.89352518554385e-03f);
  return p * __builtin_amdgcn_rcpf(qd);
}

__device__ __forceinline__ void spin_ge(int* p, int need) {
  while (__hip_atomic_load(p, __ATOMIC_ACQUIRE, __HIP_MEMORY_SCOPE_AGENT) < need)
    __builtin_amdgcn_s_sleep(2);
}

// B-fragment LDS layout (K=512 = [inp 256 | h 256]), elements are fp16:
//   B[k][n] at half-index (kt*64 + q*16 + n)*8 + j, kt=k>>5, q=(k>>3)&3, j=k&7.
//   A wave's 16B read at (kt*64+lane)*8 is exactly its 16x16x32 B-fragment.
__global__ __launch_bounds__(256, 1)
void stacked_rnn(const float* __restrict__ x,
                 const int* __restrict__ seq_lens,
                 const float* __restrict__ Wih,
                 const float* __restrict__ Whh,
                 const float* __restrict__ bias,
                 float* __restrict__ out,
                 int* flags) {
  const int ks = blockIdx.x;           // depth stage 0..2
  const int tid = (int)threadIdx.x;
  const int w = tid >> 6;              // wave 0..3 -> rows [64w, 64w+64)
  const int lane = tid & 63;
  const int q = lane >> 4;
  const int n = lane & 15;             // batch column / A-row selector

  __shared__ unsigned short Bsm[16 * 64 * 8];   // 16KB (fp16 elements)

  int* flag_up = flags + (ks - 1) * 64;
  int* flag_me = flags + ks * 64;

  // ---- persistent weight A-fragments: wf[mti][kt], kt<8 = W_ih, kt>=8 = W_hh
  h16x8 wf[4][16];
  {
    const float* wih_s = Wih + ks * (HH * HH);
    const float* whh_s = Whh + ks * (HH * HH);
#pragma unroll
    for (int mti = 0; mti < 4; ++mti) {
      const int fA = w * 64 + mti * 16 + n;      // A row = lane&15
#pragma unroll
      for (int kt = 0; kt < 16; ++kt) {
        const int col = (kt & 7) * 32 + q * 8;   // A k = quad*8 + j
        const float* src =
            (kt < 8) ? (wih_s + fA * HH + col) : (whh_s + fA * HH + col);
        float4 a0 = ((const float4*)src)[0];
        float4 a1 = ((const float4*)src)[1];
        h16x8 f;
        f[0] = (_Float16)a0.x; f[1] = (_Float16)a0.y;
        f[2] = (_Float16)a0.z; f[3] = (_Float16)a0.w;
        f[4] = (_Float16)a1.x; f[5] = (_Float16)a1.y;
        f[6] = (_Float16)a1.z; f[7] = (_Float16)a1.w;
        wf[mti][kt] = f;
      }
    }
  }

  // ---- per-lane bias in C-layout (row = q*4+r, col = n), exact fp32
  f32x4 biasv[4];
#pragma unroll
  for (int mti = 0; mti < 4; ++mti) {
#pragma unroll
    for (int r = 0; r < 4; ++r) {
      const int f = w * 64 + mti * 16 + q * 4 + r;
      biasv[mti][r] = bias[ks * HH + f];
    }
  }
  const int sl = seq_lens[n];

  // ---- zero the recurrent half of B (h_{-1} = 0): halves [4096, 8192)
  for (int i = tid; i < 4096; i += 256) Bsm[4096 + i] = 0;

  if (ks > 0 && tid == 0) spin_ge(flag_up, 24);   // covers chunk-0 prefetches
  __syncthreads();

  // ---- loader mapping: 512 chunks of 8 elems = {n 0..15} x {k8 0..31}
  const int idx0 = tid, idx1 = tid + 256;
  const int n0 = idx0 >> 5, k80 = idx0 & 31;
  const int n1 = idx1 >> 5, k81 = idx1 & 31;
  const int dst0 = ((k80 >> 2) * 64 + (k80 & 3) * 16 + n0) * 8;
  const int dst1 = ((k81 >> 2) * 64 + (k81 & 3) * 16 + n1) * 8;

  // fp32 source chunk (8 floats) -> 8 fp16 packed in uint4
  auto cvt8 = [](const float* s) -> uint4 {
    float4 a0 = ((const float4*)s)[0];
    float4 a1 = ((const float4*)s)[1];
    return make_uint4(pk2h(a0.x, a0.y), pk2h(a0.z, a0.w),
                      pk2h(a1.x, a1.y), pk2h(a1.z, a1.w));
  };

  // initial inp_0
  {
    const float* s0 = (ks == 0)
        ? (x + ((n0 * TT + 0) << 8) + (k80 << 3))
        : (out + (((n0 * TT + 0) * 3 + (ks - 1)) << 8) + (k80 << 3));
    const float* s1 = (ks == 0)
        ? (x + ((n1 * TT + 0) << 8) + (k81 << 3))
        : (out + (((n1 * TT + 0) * 3 + (ks - 1)) << 8) + (k81 << 3));
    uint4 a = cvt8(s0);
    uint4 b = cvt8(s1);
    *(uint4*)&Bsm[dst0] = a;
    *(uint4*)&Bsm[dst1] = b;
  }
  __syncthreads();

  for (int t = 0; t < TT; ++t) {
    // ---- GEMM: acc = bias + Wcat @ [inp_t ; h_{t-1}]
    f32x4 acc[4];
#pragma unroll
    for (int mti = 0; mti < 4; ++mti) acc[mti] = biasv[mti];
#pragma unroll
    for (int kt = 0; kt < 16; ++kt) {
      h16x8 bfrag = *(const h16x8*)&Bsm[(kt * 64 + lane) * 8];
#pragma unroll
      for (int mti = 0; mti < 4; ++mti)
        acc[mti] = __builtin_amdgcn_mfma_f32_16x16x32_f16(
            wf[mti][kt], bfrag, acc[mti], 0, 0, 0);
    }

    // ---- prefetch inp_{t+1} (covered by chunk-top spin: flag >= t+9 > t+2)
    uint4 npf0, npf1;
    const bool more = (t + 1 < TT);
    if (more) {
      const float* s0 = (ks == 0)
          ? (x + ((n0 * TT + (t + 1)) << 8) + (k80 << 3))
          : (out + (((n0 * TT + (t + 1)) * 3 + (ks - 1)) << 8) + (k80 << 3));
      const float* s1 = (ks == 0)
          ? (x + ((n1 * TT + (t + 1)) << 8) + (k81 << 3))
          : (out + (((n1 * TT + (t + 1)) * 3 + (ks - 1)) << 8) + (k81 << 3));
      npf0 = cvt8(s0);
      npf1 = cvt8(s1);
    }

    // ---- tanh + masked fp32 output store (h kept unmasked for recurrence)
    const bool live = (t < sl);
    uint2 hpk[4];
#pragma unroll
    for (int mti = 0; mti < 4; ++mti) {
      const float h0 = fast_tanh(acc[mti][0]);
      const float h1 = fast_tanh(acc[mti][1]);
      const float h2 = fast_tanh(acc[mti][2]);
      const float h3 = fast_tanh(acc[mti][3]);
      hpk[mti].x = pk2h(h0, h1);
      hpk[mti].y = pk2h(h2, h3);
      float4 od;
      od.x = live ? h0 : 0.0f;
      od.y = live ? h1 : 0.0f;
      od.z = live ? h2 : 0.0f;
      od.w = live ? h3 : 0.0f;
      const int f0 = w * 64 + mti * 16 + q * 4;
      *(float4*)&out[(((n * TT + t) * 3 + ks) << 8) + f0] = od;
    }

    __syncthreads();   // all B-fragment reads of step t complete

    // ---- write inp_{t+1} and pack h_t into B
    if (more) {
      *(uint4*)&Bsm[dst0] = npf0;
      *(uint4*)&Bsm[dst1] = npf1;
    }
#pragma unroll
    for (int mti = 0; mti < 4; ++mti) {
      const int kt_p = 8 + w * 2 + (mti >> 1);
      const int qpos = (mti * 2 + (q >> 1)) & 3;
      const int j0 = (q & 1) * 4;
      *(uint2*)&Bsm[(kt_p * 64 + qpos * 16 + n) * 8 + j0] = hpk[mti];
    }

    // ---- publish progress (stages 0,1) / spin for next chunk (stages 1,2)
    if (tid == 0) {
      if (ks < 2 && (t & 7) == 7)
        __hip_atomic_store(flag_me, t + 1, __ATOMIC_RELEASE,
                           __HIP_MEMORY_SCOPE_AGENT);
      if (ks > 0 && ((t + 1) & 15) == 0 && (t + 1) < TT) {
        int need = t + 25;
        if (need > TT) need = TT;
        spin_ge(flag_up, need);
      }
    }
    __syncthreads();
  }
}

extern "C" void kernel_launch(void* const* d_in, const int* in_sizes, int n_in,
                              void* d_out, int out_size, void* d_ws, size_t ws_size,
                              hipStream_t stream) {
  (void)in_sizes; (void)n_in; (void)out_size; (void)ws_size;
  const float* x   = (const float*)d_in[0];
  const int*   sl  = (const int*)d_in[1];
  const float* wih = (const float*)d_in[2];
  const float* whh = (const float*)d_in[3];
  const float* b   = (const float*)d_in[4];

  // zero the progress flags (ws is poisoned 0xAA before every launch)
  hipMemsetAsync(d_ws, 0, 1024, stream);
  hipLaunchKernelGGL(stacked_rnn, dim3(3), dim3(256), 0, stream,
                     x, sl, wih, whh, b, (float*)d_out, (int*)d_ws);
}

// Round 5
// 2303.171 us; speedup vs baseline: 2.5526x; 2.5526x over previous
//
#include <hip/hip_runtime.h>
#include <stdint.h>

// StackedRNN depth-3, B=16, T=2048, H=256. Inputs fp32, output fp32.
// 3 persistent workgroups (one per depth), 512 threads (8 waves, 2/SIMD).
// Weights fp16-resident in VGPRs (wf[2][16] = 128 VGPR/lane), batch=16 in
// MFMA N, depth pipelined through d_out with agent-scope progress flags.
// Single barrier/step (ping-pong LDS B), XOR-swizzled LDS (conflict-free),
// exp2-based tanh, 2-step-deep global prefetch.

#define TT 2048
#define HH 256

typedef _Float16 h16x8 __attribute__((ext_vector_type(8)));
typedef float f32x4 __attribute__((ext_vector_type(4)));

__device__ __forceinline__ unsigned pkrtz(float a, float b) {
  return __builtin_bit_cast(unsigned, __builtin_amdgcn_cvt_pkrtz(a, b));
}

// tanh(x) = 1 - 2e/(1+e), e = e^{-2x} = exp2(-2*log2(e)*x).  ~1e-6 err.
// clamp low side so e stays finite (avoids inf*0 NaN).
__device__ __forceinline__ float tanh_fast(float x) {
  float xm = fmaxf(x, -15.0f);
  float e = __builtin_amdgcn_exp2f(xm * -2.88539008177793f);
  float r = __builtin_amdgcn_rcpf(1.0f + e);
  return __builtin_fmaf(-2.0f * e, r, 1.0f);
}

__device__ __forceinline__ void spin_ge(int* p, int need) {
  while (__hip_atomic_load(p, __ATOMIC_ACQUIRE, __HIP_MEMORY_SCOPE_AGENT) < need)
    __builtin_amdgcn_s_sleep(2);
}

// LDS B layout (fp16, K=512 = [inp 256 | h 256]):
//   granule (16B) for (k,n): u = (k>>5)*4 + ((k>>3)&3), v = n, j = k&7
//   half-index = (u*16 + (v ^ (u&7)))*8 + j     (XOR swizzle kills write
//   conflicts; reads at fixed u keep all 16 v' distinct -> conflict-free)
__global__ __launch_bounds__(512, 2)
void stacked_rnn(const float* __restrict__ x,
                 const int* __restrict__ seq_lens,
                 const float* __restrict__ Wih,
                 const float* __restrict__ Whh,
                 const float* __restrict__ bias,
                 float* __restrict__ out,
                 int* flags) {
  const int ks = blockIdx.x;           // depth stage 0..2
  const int tid = (int)threadIdx.x;
  const int w = tid >> 6;              // wave 0..7 -> rows [32w, 32w+32)
  const int lane = tid & 63;
  const int q = lane >> 4;
  const int n = lane & 15;             // batch column

  __shared__ unsigned short Bsm[2][8192];   // 2 x 16KB ping-pong

  int* flag_up = flags + (ks - 1) * 64;
  int* flag_me = flags + ks * 64;

  // ---- persistent weight A-fragments (fp16, RTN): kt<8 = W_ih, kt>=8 = W_hh
  h16x8 wf[2][16];
  {
    const float* wih_s = Wih + ks * (HH * HH);
    const float* whh_s = Whh + ks * (HH * HH);
#pragma unroll
    for (int mti = 0; mti < 2; ++mti) {
      const int fA = w * 32 + mti * 16 + n;      // A row = lane&15
#pragma unroll
      for (int kt = 0; kt < 16; ++kt) {
        const int col = (kt & 7) * 32 + q * 8;   // A k = quad*8 + j
        const float* src = (kt < 8) ? (wih_s + fA * HH + col)
                                    : (whh_s + fA * HH + col);
        float4 a0 = ((const float4*)src)[0];
        float4 a1 = ((const float4*)src)[1];
        h16x8 f;
        f[0] = (_Float16)a0.x; f[1] = (_Float16)a0.y;
        f[2] = (_Float16)a0.z; f[3] = (_Float16)a0.w;
        f[4] = (_Float16)a1.x; f[5] = (_Float16)a1.y;
        f[6] = (_Float16)a1.z; f[7] = (_Float16)a1.w;
        wf[mti][kt] = f;
      }
    }
  }

  // ---- bias in C-layout (row = q*4+r, col = n), exact fp32
  f32x4 biasv[2];
#pragma unroll
  for (int mti = 0; mti < 2; ++mti)
#pragma unroll
    for (int r = 0; r < 4; ++r)
      biasv[mti][r] = bias[ks * HH + w * 32 + mti * 16 + q * 4 + r];

  const int sl = seq_lens[n];

  // ---- fragment read offsets (halves): frag kt at rd{E,O} + kt*512
  const int rdE = (q * 16 + (n ^ q)) * 8;        // even kt: u&7 = q
  const int rdO = (q * 16 + (n ^ q ^ 4)) * 8;    // odd  kt: u&7 = q+4

  // ---- h-repack write offsets (uint2 = 4 halves, j0 = (q&1)*4)
  int hofs[2];
#pragma unroll
  for (int mti = 0; mti < 2; ++mti) {
    const int u = (8 + w) * 4 + mti * 2 + (q >> 1);
    hofs[mti] = (u * 16 + (n ^ (u & 7))) * 8 + (q & 1) * 4;
  }

  // ---- loader: 512 chunks of 8 floats = {n 0..15} x {k8 0..31}, 1/thread
  const int n_l = tid >> 5;
  const int k8  = tid & 31;
  const int u_l = (k8 >> 2) * 4 + (k8 & 3);
  const int ldst = (u_l * 16 + (n_l ^ (u_l & 7))) * 8;

  const float* src_base;
  int src_stride;
  if (ks == 0) {
    src_base = x + ((n_l * TT) << 8) + (k8 << 3);
    src_stride = HH;
  } else {
    src_base = out + (((n_l * TT) * 3 + (ks - 1)) << 8) + (k8 << 3);
    src_stride = 3 * HH;
  }

  // ---- zero h-half of buf0 (h_{-1} = 0)
  for (int i = tid; i < 4096; i += 512) Bsm[0][4096 + i] = 0;
  if (ks > 0 && tid == 0) spin_ge(flag_up, 18);   // covers preload + chunk 0
  __syncthreads();

  // ---- preload inp_0 -> buf0, inp_1 -> pfB, pf pointer at t=2
  {
    float4 c0 = ((const float4*)src_base)[0];
    float4 c1 = ((const float4*)src_base)[1];
    *(uint4*)&Bsm[0][ldst] = make_uint4(pkrtz(c0.x, c0.y), pkrtz(c0.z, c0.w),
                                        pkrtz(c1.x, c1.y), pkrtz(c1.z, c1.w));
  }
  float4 pfB0 = ((const float4*)(src_base + src_stride))[0];
  float4 pfB1 = ((const float4*)(src_base + src_stride))[1];
  const float* src_pf = src_base + 2 * src_stride;
  __syncthreads();

  float* outp = out + ((n * TT) * 3 + ks) * HH + w * 32 + q * 4;

  for (int t = 0; t < TT; ++t) {
    unsigned short* Bp = Bsm[t & 1];
    unsigned short* Bq = Bsm[(t & 1) ^ 1];

    // ---- publish (multiples of 8; h_{t-1} drained by last iter's barrier)
    if ((t & 7) == 0 && t > 0 && ks < 2 && tid == 0)
      __hip_atomic_store(flag_me, t, __ATOMIC_RELEASE,
                         __HIP_MEMORY_SCOPE_AGENT);
    // ---- chunk gate: iters t..t+15 load steps t+2..t+17 -> need flag t+18
    if ((t & 15) == 0 && t > 0 && ks > 0) {
      if (tid == 0) {
        int need = t + 18;
        if (need > TT) need = TT;
        spin_ge(flag_up, need);
      }
      __syncthreads();
    }

    // ---- issue global prefetch for inp_{t+2} (drained at this iter's barrier)
    float4 pfA0, pfA1;
    const bool more2 = (t + 2 < TT);
    if (more2) {
      pfA0 = ((const float4*)src_pf)[0];
      pfA1 = ((const float4*)src_pf)[1];
    }
    src_pf += src_stride;

    // ---- GEMM: acc = bias + Wcat @ [inp_t ; h_{t-1}]
    f32x4 acc[2] = {biasv[0], biasv[1]};
#pragma unroll
    for (int kt = 0; kt < 16; ++kt) {
      const int ofs = ((kt & 1) ? rdO : rdE) + kt * 512;
      h16x8 bf = *(const h16x8*)&Bp[ofs];
      acc[0] = __builtin_amdgcn_mfma_f32_16x16x32_f16(wf[0][kt], bf, acc[0], 0, 0, 0);
      acc[1] = __builtin_amdgcn_mfma_f32_16x16x32_f16(wf[1][kt], bf, acc[1], 0, 0, 0);
    }

    // ---- tanh + masked fp32 output store (h kept unmasked for recurrence)
    const bool live = (t < sl);
    uint2 hpk[2];
#pragma unroll
    for (int mti = 0; mti < 2; ++mti) {
      float h0 = tanh_fast(acc[mti][0]);
      float h1 = tanh_fast(acc[mti][1]);
      float h2 = tanh_fast(acc[mti][2]);
      float h3 = tanh_fast(acc[mti][3]);
      hpk[mti].x = pkrtz(h0, h1);
      hpk[mti].y = pkrtz(h2, h3);
      float4 od;
      od.x = live ? h0 : 0.0f;
      od.y = live ? h1 : 0.0f;
      od.z = live ? h2 : 0.0f;
      od.w = live ? h3 : 0.0f;
      *(float4*)(outp + mti * 16) = od;
    }
    outp += 3 * HH;

    // ---- write buf p^1: inp_{t+1} (from pfB) + h_t (repack)
    if (t + 1 < TT) {
      *(uint4*)&Bq[ldst] = make_uint4(pkrtz(pfB0.x, pfB0.y), pkrtz(pfB0.z, pfB0.w),
                                      pkrtz(pfB1.x, pfB1.y), pkrtz(pfB1.z, pfB1.w));
      *(uint2*)&Bq[hofs[0]] = hpk[0];
      *(uint2*)&Bq[hofs[1]] = hpk[1];
      if (more2) { pfB0 = pfA0; pfB1 = pfA1; }
    }

    __syncthreads();   // the one per-step barrier
  }

  if (ks < 2 && tid == 0)
    __hip_atomic_store(flag_me, TT, __ATOMIC_RELEASE, __HIP_MEMORY_SCOPE_AGENT);
}

extern "C" void kernel_launch(void* const* d_in, const int* in_sizes, int n_in,
                              void* d_out, int out_size, void* d_ws, size_t ws_size,
                              hipStream_t stream) {
  (void)in_sizes; (void)n_in; (void)out_size; (void)ws_size;
  const float* x   = (const float*)d_in[0];
  const int*   sl  = (const int*)d_in[1];
  const float* wih = (const float*)d_in[2];
  const float* whh = (const float*)d_in[3];
  const float* b   = (const float*)d_in[4];

  // zero the progress flags (ws is poisoned 0xAA before every launch)
  (void)hipMemsetAsync(d_ws, 0, 1024, stream);
  hipLaunchKernelGGL(stacked_rnn, dim3(3), dim3(512), 0, stream,
                     x, sl, wih, whh, b, (float*)d_out, (int*)d_ws);
}